// Round 15
// baseline (373.366 us; speedup 1.0000x reference)
//
#include <hip/hip_runtime.h>
#include <hip/hip_bf16.h>

// RGCN encoder: N=100000, E=128, R=9, L=3, NE=640000. Only the LAST layer
// matters (reference resets hidden=embeddings each layer).
//   out[n] = sum_{e:dst=n}(W_t h[src]+b_t) + sum_{e:src=n}(W_{t+9} h[dst]+b_{t+9})
// AGGREGATE-FIRST (linearity): out[d] = sum_t W_t * M_t[d] + deg_t(d)*b_t.
// Round-15: r14's bf16 LDS RMW cost ~40 VALU/record (unpack+add+repack) and
// 8M bank-conflict cycles. Now accumulate in FP32 LDS (Mt [16][396] floats,
// 25.3KB): RMW = 2x ds_read_b128 + 8 lshl + 8 add + 2x ds_write_b128
// (~16 VALU, no packing, better precision). Before MFMA each lane converts
// its OWN 24 floats to a bf16 view in place (read-own / barrier / write /
// barrier -- ownership makes it race-free). 6 blocks/CU (~75% occ).
// Streaming loop, (node,type)-sorted CSR, MFMA, deg*b epilogue: as r14.

#define E_DIM 128
#define R_REL 9
#define TN 16        // nodes per fused block
#define TCH 3        // types per chunk
#define PF 396       // f32 Mt pitch in floats (384 used + 12 pad; 16B-mult)
#define MT_PB 392    // bf16 view pitch in ushorts (384 used + 8 pad)
#define SCB 1024     // elements per scan block
#define NSLICE 96    // edge slices per octant in count/fill

typedef __attribute__((ext_vector_type(8))) short short8v;
typedef __attribute__((ext_vector_type(4))) float f32x4;

static __device__ __forceinline__ unsigned short f2bf(float f) {
    union { float f; unsigned u; } v; v.f = f;
    unsigned u = v.u;
    return (unsigned short)((u + 0x7FFFu + ((u >> 16) & 1u)) >> 16);
}
static __device__ __forceinline__ float bf2f(unsigned short h) {
    union { unsigned u; float f; } v; v.u = ((unsigned)h) << 16;
    return v.f;
}

// ---------- fast path ----------

// Combined prep: blocks 0..17 swizzle W into MFMA fragment order; blocks 18..
// convert H fp32 -> bf16.
__global__ __launch_bounds__(256) void prep(
    const float* __restrict__ H, const float* __restrict__ W18,
    unsigned short* __restrict__ Hbf, unsigned short* __restrict__ Wt,
    long total8)
{
    const int tid = threadIdx.x;
    if (blockIdx.x < 18) {
        const int rel = blockIdx.x;
        const float* __restrict__ Wr = W18 + (size_t)rel * E_DIM * E_DIM;
#pragma unroll
        for (int k = 0; k < 8; k++) {
            int f = tid + k * 256;            // 0..2047
            int lane = f & 63;
            int c = (f >> 6) & 1;
            int s = (f >> 7) & 3;
            int w = (f >> 9) & 3;
            int col = w * 32 + c * 16 + (lane & 15);
            int kb = s * 32 + (lane >> 4) * 8;
            short8v v;
#pragma unroll
            for (int j = 0; j < 8; j++)
                v[j] = (short)f2bf(Wr[(size_t)(kb + j) * E_DIM + col]);
            *(short8v*)(Wt + ((size_t)((((rel * 4 + w) * 4 + s) * 2 + c) * 64 + lane)) * 8) = v;
        }
    } else {
        long i = (long)(blockIdx.x - 18) * 256 + tid;
        if (i >= total8) return;
        const float4* src = (const float4*)(H + i * 8);
        float4 a = src[0], b = src[1];
        short8v o;
        o[0] = (short)f2bf(a.x); o[1] = (short)f2bf(a.y);
        o[2] = (short)f2bf(a.z); o[3] = (short)f2bf(a.w);
        o[4] = (short)f2bf(b.x); o[5] = (short)f2bf(b.y);
        o[6] = (short)f2bf(b.z); o[7] = (short)f2bf(b.w);
        *(short8v*)(Hbf + i * 8) = o;
    }
}

// CSR over n3 = 2*Nn*9 (node,dir,type) segments; key = seg*9+t, seg = d (fwd)
// or Nn+s (bwd). Octant-partitioned by node: counter window L2-local.
__global__ __launch_bounds__(256) void k_count8(
    const int* __restrict__ esrc, const int* __restrict__ edst,
    const int* __restrict__ etype, int* __restrict__ cnt, int ne, int Nn)
{
    const int oct = blockIdx.x & 7;
    const int slice = blockIdx.x >> 3;
    const int lo = (int)(((long long)oct * Nn) >> 3);
    const int hi = (int)(((long long)(oct + 1) * Nn) >> 3);
    for (int e = slice * 256 + threadIdx.x; e < ne; e += NSLICE * 256) {
        int t = etype[e], s = esrc[e], d = edst[e];
        if (d >= lo && d < hi) atomicAdd(&cnt[d * R_REL + t], 1);
        if (s >= lo && s < hi) atomicAdd(&cnt[(Nn + s) * R_REL + t], 1);
    }
}

// Hierarchical scan, 3 kernels (r5-validated).
__global__ __launch_bounds__(256) void k_scan_part(
    const int* __restrict__ cnt, int* __restrict__ loc,
    int* __restrict__ bsum, int n2)
{
    __shared__ int sh[256];
    const int tid = threadIdx.x;
    const int i0 = blockIdx.x * SCB + tid * 4;
    int v0 = 0, v1 = 0, v2 = 0, v3 = 0;
    if (i0 + 3 < n2) {
        int4 v = *(const int4*)(cnt + i0);
        v0 = v.x; v1 = v.y; v2 = v.z; v3 = v.w;
    } else {
        if (i0 + 0 < n2) v0 = cnt[i0 + 0];
        if (i0 + 1 < n2) v1 = cnt[i0 + 1];
        if (i0 + 2 < n2) v2 = cnt[i0 + 2];
        if (i0 + 3 < n2) v3 = cnt[i0 + 3];
    }
    int t = v0 + v1 + v2 + v3;
    sh[tid] = t;
    __syncthreads();
    for (int o = 1; o < 256; o <<= 1) {
        int x = (tid >= o) ? sh[tid - o] : 0;
        __syncthreads();
        sh[tid] += x;
        __syncthreads();
    }
    int excl = sh[tid] - t;
    if (tid == 255) bsum[blockIdx.x] = sh[255];
    int p0 = excl, p1 = p0 + v0, p2 = p1 + v1, p3 = p2 + v2;
    if (i0 + 3 < n2) {
        *(int4*)(loc + i0) = make_int4(p0, p1, p2, p3);
    } else {
        if (i0 + 0 < n2) loc[i0 + 0] = p0;
        if (i0 + 1 < n2) loc[i0 + 1] = p1;
        if (i0 + 2 < n2) loc[i0 + 2] = p2;
        if (i0 + 3 < n2) loc[i0 + 3] = p3;
    }
}

__global__ __launch_bounds__(256) void k_scan_mid(int* __restrict__ bsum, int nb)
{
    __shared__ int sh[256];
    __shared__ int carry;
    const int tid = threadIdx.x;
    if (tid == 0) carry = 0;
    __syncthreads();
    for (int base = 0; base < nb; base += 256) {
        int i = base + tid;
        int v = (i < nb) ? bsum[i] : 0;
        sh[tid] = v;
        __syncthreads();
        for (int o = 1; o < 256; o <<= 1) {
            int x = (tid >= o) ? sh[tid - o] : 0;
            __syncthreads();
            sh[tid] += x;
            __syncthreads();
        }
        int excl = sh[tid] - v + carry;
        int total = sh[255];
        if (i < nb) bsum[i] = excl;
        __syncthreads();
        if (tid == 0) carry += total;
        __syncthreads();
    }
}

__global__ __launch_bounds__(256) void k_scan_apply(
    const int* __restrict__ loc, const int* __restrict__ bsum,
    int* __restrict__ off, int* __restrict__ cursor, int n2)
{
    const int add = bsum[blockIdx.x];
    const int i0 = blockIdx.x * SCB + threadIdx.x * 4;
    if (i0 + 3 < n2) {
        int4 v = *(const int4*)(loc + i0);
        v.x += add; v.y += add; v.z += add; v.w += add;
        *(int4*)(off + i0) = v;
        *(int4*)(cursor + i0) = v;
    } else {
#pragma unroll
        for (int j = 0; j < 4; j++)
            if (i0 + j < n2) {
                int v = loc[i0 + j] + add;
                off[i0 + j] = v;
                cursor[i0 + j] = v;
            }
    }
}

// rec = (t<<20) | otherNode, via (node,t) cursor -> type-grouped per node.
__global__ __launch_bounds__(256) void k_fill8(
    const int* __restrict__ esrc, const int* __restrict__ edst,
    const int* __restrict__ etype, int* __restrict__ cursor,
    unsigned* __restrict__ rec, int ne, int Nn)
{
    const int oct = blockIdx.x & 7;
    const int slice = blockIdx.x >> 3;
    const int lo = (int)(((long long)oct * Nn) >> 3);
    const int hi = (int)(((long long)(oct + 1) * Nn) >> 3);
    for (int e = slice * 256 + threadIdx.x; e < ne; e += NSLICE * 256) {
        int t = etype[e], s = esrc[e], d = edst[e];
        if (d >= lo && d < hi) {
            int p = atomicAdd(&cursor[d * R_REL + t], 1);
            rec[p] = ((unsigned)t << 20) | (unsigned)s;   // fwd msg into d
        }
        if (s >= lo && s < hi) {
            int p2 = atomicAdd(&cursor[(Nn + s) * R_REL + t], 1);
            rec[p2] = ((unsigned)t << 20) | (unsigned)d;  // bwd msg into s
        }
    }
}

// Fused aggregate+GEMM, K split in 3 type-chunks, FP32 LDS accumulation.
// Block = 16 nodes, 4 waves; LDS ~26.5KB -> 6 blocks/CU (~75% occ).
// Per dir, per chunk:
//   zero own f32 Mt rows; group g streams node w*4+g's records of types
//   [3c,3c+3) (4-deep predicated, short8/lane); fp32 LDS RMW (b128 pair);
//   convert: read OWN 24 floats -> regs, barrier, write bf16 view, barrier;
//   MFMA acc += Mtb_chunk @ W[dir,chunk] (swapped operands); barrier.
// Epilogue: + deg_t*b_t both dirs, single fp32 out store.
__global__ __launch_bounds__(256, 6) void fused_rgcn(
    const unsigned short* __restrict__ Hbf, const unsigned short* __restrict__ Wt,
    const float* __restrict__ B18,
    const int* __restrict__ off3, const int* __restrict__ cur3,
    const unsigned* __restrict__ rec,
    float* __restrict__ out, int Nn)
{
    __shared__ __align__(16) float MtF[TN * PF];     // f32 accum (25.3KB)
    __shared__ float degS[2][TN][R_REL];

    unsigned short* Mtb = (unsigned short*)MtF;      // bf16 view, pitch MT_PB

    const int tid = threadIdx.x;
    const int lane = tid & 63;
    const int w = tid >> 6;             // wave id; col slice w*32..w*32+31
    const int lr = lane & 15;
    const int lg = lane >> 4;
    const int grp = lg;                 // node-in-wave (aggregation role)
    const int gl = lr;                  // channel sub-lane: ch gl*8..gl*8+7
    const int n0 = blockIdx.x * TN;

    const short8v* wt8 = (const short8v*)Wt;
    const short8v z8 = (short8v){0, 0, 0, 0, 0, 0, 0, 0};
    const f32x4 zf = (f32x4){0.f, 0.f, 0.f, 0.f};

    f32x4 acc[2];
    acc[0] = zf;
    acc[1] = zf;

#define RMW(rk, vk)                                                           \
    {                                                                         \
        int _tl = (int)((rk) >> 20) - tbase;                                  \
        float* _mp = MtF + (size_t)(w * 4 + grp) * PF + _tl * E_DIM + gl * 8; \
        f32x4 _m0 = *(f32x4*)_mp;                                             \
        f32x4 _m1 = *(f32x4*)(_mp + 4);                                       \
        _Pragma("unroll")                                                     \
        for (int _c = 0; _c < 4; _c++) {                                      \
            _m0[_c] += bf2f((unsigned short)(vk)[_c]);                        \
            _m1[_c] += bf2f((unsigned short)(vk)[_c + 4]);                    \
        }                                                                     \
        *(f32x4*)_mp = _m0;                                                   \
        *(f32x4*)(_mp + 4) = _m1;                                             \
    }

#pragma unroll 1
    for (int dir = 0; dir < 2; dir++) {
        // Prefetch bounds: lane = jj*16 + tt (jj = node-in-wave, tt = type).
        const int jj = lg, tt = lr;
        const int gnode_j = n0 + w * 4 + jj;
        int blo = 0x7F000000, bhi = 0x7F000000;
        if (gnode_j < Nn && tt < R_REL) {
            size_t sb = ((size_t)(dir ? (Nn + gnode_j) : gnode_j)) * R_REL + tt;
            blo = off3[sb];
            bhi = cur3[sb];
            degS[dir][w * 4 + jj][tt] = (float)(bhi - blo);
        }

#pragma unroll 1
        for (int ch = 0; ch < 3; ch++) {
            const int tbase = ch * TCH;

            // Zero this wave's f32 Mt rows (384 used floats = 96 f32x4/row).
#pragma unroll
            for (int rr = 0; rr < 4; rr++) {
                float* rowp = MtF + (size_t)(w * 4 + rr) * PF;
                *(f32x4*)(rowp + (size_t)lane * 4) = zf;
                if (lane < 32) *(f32x4*)(rowp + (size_t)(lane + 64) * 4) = zf;
            }

            // Per-group record range for this chunk (types tbase..tbase+2).
            const int st_g = __shfl(blo, grp * 16 + tbase);
            const int en_g = __shfl(bhi, grp * 16 + tbase + TCH - 1);

            int ii = st_g;
            while (__any(ii < en_g)) {
                bool a0 = ii + 0 < en_g;
                bool a1 = ii + 1 < en_g;
                bool a2 = ii + 2 < en_g;
                bool a3 = ii + 3 < en_g;
                unsigned r0 = 0, r1 = 0, r2 = 0, r3 = 0;
                if (a0) r0 = rec[ii + 0];
                if (a1) r1 = rec[ii + 1];
                if (a2) r2 = rec[ii + 2];
                if (a3) r3 = rec[ii + 3];
                short8v v0 = z8, v1 = z8, v2 = z8, v3 = z8;
                if (a0) v0 = *(const short8v*)(Hbf + (size_t)(r0 & 0xFFFFF) * E_DIM + gl * 8);
                if (a1) v1 = *(const short8v*)(Hbf + (size_t)(r1 & 0xFFFFF) * E_DIM + gl * 8);
                if (a2) v2 = *(const short8v*)(Hbf + (size_t)(r2 & 0xFFFFF) * E_DIM + gl * 8);
                if (a3) v3 = *(const short8v*)(Hbf + (size_t)(r3 & 0xFFFFF) * E_DIM + gl * 8);
                if (a0) RMW(r0, v0);
                if (a1) RMW(r1, v1);
                if (a2) RMW(r2, v2);
                if (a3) RMW(r3, v3);
                ii += 4;
            }

            // Convert own 24 floats -> bf16 view (race-free by ownership).
            const float* mrow = MtF + (size_t)(w * 4 + grp) * PF + gl * 8;
            f32x4 c0a = *(const f32x4*)(mrow + 0 * E_DIM);
            f32x4 c0b = *(const f32x4*)(mrow + 0 * E_DIM + 4);
            f32x4 c1a = *(const f32x4*)(mrow + 1 * E_DIM);
            f32x4 c1b = *(const f32x4*)(mrow + 1 * E_DIM + 4);
            f32x4 c2a = *(const f32x4*)(mrow + 2 * E_DIM);
            f32x4 c2b = *(const f32x4*)(mrow + 2 * E_DIM + 4);
            __syncthreads();   // all f32 reads done before bf16 writes overlap
            unsigned short* brow = Mtb + (size_t)(w * 4 + grp) * MT_PB + gl * 8;
            short8v o0, o1, o2;
#pragma unroll
            for (int c = 0; c < 4; c++) {
                o0[c] = (short)f2bf(c0a[c]); o0[c + 4] = (short)f2bf(c0b[c]);
                o1[c] = (short)f2bf(c1a[c]); o1[c + 4] = (short)f2bf(c1b[c]);
                o2[c] = (short)f2bf(c2a[c]); o2[c + 4] = (short)f2bf(c2b[c]);
            }
            *(short8v*)(brow + 0 * E_DIM) = o0;
            *(short8v*)(brow + 1 * E_DIM) = o1;
            *(short8v*)(brow + 2 * E_DIM) = o2;
            __syncthreads();

            // ---- GEMM: acc += Mtb_chunk @ W[dir, chunk types] ----
#pragma unroll
            for (int q = 0; q < TCH; q++) {
                const int rel = dir * R_REL + tbase + q;
#pragma unroll
                for (int s = 0; s < 4; s++) {
                    short8v b0 = wt8[(size_t)((((rel * 4 + w) * 4 + s) * 2 + 0) * 64) + lane];
                    short8v b1 = wt8[(size_t)((((rel * 4 + w) * 4 + s) * 2 + 1) * 64) + lane];
                    short8v a = *(const short8v*)(&Mtb[(size_t)lr * MT_PB + q * E_DIM + s * 32 + lg * 8]);
                    acc[0] = __builtin_amdgcn_mfma_f32_16x16x32_bf16(b0, a, acc[0], 0, 0, 0);
                    acc[1] = __builtin_amdgcn_mfma_f32_16x16x32_bf16(b1, a, acc[1], 0, 0, 0);
                }
            }
            __syncthreads();   // before next chunk's zero overwrites views
        }
    }
#undef RMW

    // ---- epilogue: bias (deg_t * b_t) + store ----
    const int gnode = n0 + lr;
    if (gnode >= Nn) return;
#pragma unroll 1
    for (int dir = 0; dir < 2; dir++) {
#pragma unroll 1
        for (int t = 0; t < R_REL; t++) {
            float dg = degS[dir][lr][t];
            if (dg != 0.f) {
                const float* brow = B18 + (size_t)(dir * R_REL + t) * E_DIM + w * 32 + lg * 4;
                float4 b0 = *(const float4*)(brow);
                float4 b1 = *(const float4*)(brow + 16);
                acc[0][0] += dg * b0.x; acc[0][1] += dg * b0.y;
                acc[0][2] += dg * b0.z; acc[0][3] += dg * b0.w;
                acc[1][0] += dg * b1.x; acc[1][1] += dg * b1.y;
                acc[1][2] += dg * b1.z; acc[1][3] += dg * b1.w;
            }
        }
    }
    float* po = out + (size_t)gnode * E_DIM + w * 32 + lg * 4;
    *(float4*)po = make_float4(acc[0][0], acc[0][1], acc[0][2], acc[0][3]);
    *(float4*)(po + 16) = make_float4(acc[1][0], acc[1][1], acc[1][2], acc[1][3]);
}

// ---------- zero-workspace fallback (round-1, validated) ----------

__global__ __launch_bounds__(128) void direct_edge(
    const int* __restrict__ esrc, const int* __restrict__ edst,
    const int* __restrict__ etype,
    const float* __restrict__ H, const float* __restrict__ W2,
    const float* __restrict__ B2, float* __restrict__ out, int ne)
{
    __shared__ float hs[E_DIM];
    __shared__ float hd[E_DIM];
    int e = blockIdx.x;
    if (e >= ne) return;
    int t = etype[e], s = esrc[e], d = edst[e];
    int c = threadIdx.x;
    hs[c] = H[(size_t)s * E_DIM + c];
    hd[c] = H[(size_t)d * E_DIM + c];
    __syncthreads();
    const float* Wf = W2 + (size_t)t * E_DIM * E_DIM;
    const float* Wb = W2 + (size_t)(t + R_REL) * E_DIM * E_DIM;
    float accf = B2[(size_t)t * E_DIM + c];
    float accb = B2[(size_t)(t + R_REL) * E_DIM + c];
#pragma unroll 8
    for (int k = 0; k < E_DIM; k++) {
        accf += hs[k] * Wf[(size_t)k * E_DIM + c];
        accb += hd[k] * Wb[(size_t)k * E_DIM + c];
    }
    atomicAdd(&out[(size_t)d * E_DIM + c], accf);
    atomicAdd(&out[(size_t)s * E_DIM + c], accb);
}

extern "C" void kernel_launch(void* const* d_in, const int* in_sizes, int n_in,
                              void* d_out, int out_size, void* d_ws, size_t ws_size,
                              hipStream_t stream) {
    const int* edge_index = (const int*)d_in[0];   // [2][NE]
    const int* edge_type  = (const int*)d_in[1];   // [NE]
    const float* emb      = (const float*)d_in[2]; // [N][128]
    const float* weights  = (const float*)d_in[3]; // [L][18][128][128]
    const float* biases   = (const float*)d_in[4]; // [L][18][128]
    float* out = (float*)d_out;

    const int NE = in_sizes[1];
    const int Nn = in_sizes[2] / E_DIM;
    const int L  = in_sizes[3] / (2 * R_REL * E_DIM * E_DIM);

    const float* W2 = weights + (size_t)(L - 1) * 2 * R_REL * E_DIM * E_DIM;
    const float* B2 = biases  + (size_t)(L - 1) * 2 * R_REL * E_DIM;

    const int* esrc = edge_index;
    const int* edst = edge_index + NE;

    const int n3 = 2 * Nn * R_REL;                 // (node,dir,type) segments
    const int nb3 = (n3 + SCB - 1) / SCB;

    auto al = [](size_t x) { return (x + 255) & ~(size_t)255; };
    const size_t hbfBytes = al((size_t)Nn * E_DIM * 2);
    const size_t wtBytes  = al((size_t)2 * R_REL * E_DIM * E_DIM * 2);
    const size_t offBytes = al((size_t)n3 * 4);
    const size_t curBytes = al((size_t)n3 * 4);
    const size_t recBytes = al((size_t)2 * NE * 4);
    const size_t bsBytes  = al((size_t)nb3 * 4);
    const size_t need = hbfBytes + wtBytes + offBytes + curBytes + recBytes + bsBytes;

    if (ws_size >= need && Nn < (1 << 20)) {
        char* p = (char*)d_ws;
        unsigned short* Hbf = (unsigned short*)p;        p += hbfBytes;
        unsigned short* Wt  = (unsigned short*)p;        p += wtBytes;
        int* off3           = (int*)p;                   p += offBytes;
        int* cur3           = (int*)p;                   p += curBytes;
        unsigned* rec       = (unsigned*)p;              p += recBytes;
        int* bsum           = (int*)p;

        const long total8 = (long)Nn * (E_DIM / 8);
        const int hblocks = (int)((total8 + 255) / 256);

        hipMemsetAsync(off3, 0, (size_t)n3 * 4, stream);
        prep<<<18 + hblocks, 256, 0, stream>>>(emb, W2, Hbf, Wt, total8);
        k_count8<<<8 * NSLICE, 256, 0, stream>>>(esrc, edst, edge_type, off3, NE, Nn);
        k_scan_part<<<nb3, 256, 0, stream>>>(off3, cur3, bsum, n3);
        k_scan_mid<<<1, 256, 0, stream>>>(bsum, nb3);
        k_scan_apply<<<nb3, 256, 0, stream>>>(cur3, bsum, off3, cur3, n3);
        k_fill8<<<8 * NSLICE, 256, 0, stream>>>(esrc, edst, edge_type,
                                                cur3, rec, NE, Nn);

        fused_rgcn<<<(Nn + TN - 1) / TN, 256, 0, stream>>>(
            Hbf, Wt, B2, off3, cur3, rec, out, Nn);
        return;
    }

    // Fallback: direct per-edge GEMV with atomics.
    hipMemsetAsync(d_out, 0, (size_t)Nn * E_DIM * sizeof(float), stream);
    direct_edge<<<NE, 128, 0, stream>>>(esrc, edst, edge_type, emb, W2, B2, out, NE);
}

// Round 16
// 348.125 us; speedup vs baseline: 1.0725x; 1.0725x over previous
//
#include <hip/hip_runtime.h>
#include <hip/hip_bf16.h>

// RGCN encoder: N=100000, E=128, R=9, L=3, NE=640000. Only the LAST layer
// matters (reference resets hidden=embeddings each layer).
//   out[n] = sum_{e:dst=n}(W_t h[src]+b_t) + sum_{e:src=n}(W_{t+9} h[dst]+b_{t+9})
// AGGREGATE-FIRST (linearity): out[d] = sum_t W_t * M_t[d] + deg_t(d)*b_t.
// Round-16: r14 config (bf16 LDS RMW, 3 type-chunks, 13.8KB LDS, 8 blk/CU)
// was best (fused 218us) but occupancy read 78% -- grid 6250 over 2048
// resident slots = 3.05 rounds, fractional round runs near-empty (tail).
// Fix: PERSISTENT grid-stride blocks (2048 launched, loop over tiles).
// Also fuse prep + count into one partitioned launch. r15's fp32-LDS
// variant reverted (occupancy loss + doubled LDS cycles).

#define E_DIM 128
#define R_REL 9
#define TN 16        // nodes per fused block
#define TCH 3        // types per chunk
#define MT_P2 392    // Mt pitch in ushorts (384 used + 8 pad)
#define SCB 1024     // elements per scan block
#define NSLICE 96    // edge slices per octant in count/fill

typedef __attribute__((ext_vector_type(8))) short short8v;
typedef __attribute__((ext_vector_type(4))) float f32x4;

static __device__ __forceinline__ unsigned short f2bf(float f) {
    union { float f; unsigned u; } v; v.f = f;
    unsigned u = v.u;
    return (unsigned short)((u + 0x7FFFu + ((u >> 16) & 1u)) >> 16);
}
static __device__ __forceinline__ float bf2f(unsigned short h) {
    union { unsigned u; float f; } v; v.u = ((unsigned)h) << 16;
    return v.f;
}

// ---------- fast path ----------

// Fused prep + count: blocks [0,18) swizzle W into MFMA fragment order;
// [18, 18+hblocks) convert H fp32->bf16; rest: octant-partitioned count
// over (node,dir,type) segments (all three are independent).
__global__ __launch_bounds__(256) void prep_count(
    const float* __restrict__ H, const float* __restrict__ W18,
    const int* __restrict__ esrc, const int* __restrict__ edst,
    const int* __restrict__ etype,
    unsigned short* __restrict__ Hbf, unsigned short* __restrict__ Wt,
    int* __restrict__ cnt, long total8, int hblocks, int ne, int Nn)
{
    const int tid = threadIdx.x;
    const int b = blockIdx.x;
    if (b < 18) {
        const int rel = b;
        const float* __restrict__ Wr = W18 + (size_t)rel * E_DIM * E_DIM;
#pragma unroll
        for (int k = 0; k < 8; k++) {
            int f = tid + k * 256;            // 0..2047
            int lane = f & 63;
            int c = (f >> 6) & 1;
            int s = (f >> 7) & 3;
            int w = (f >> 9) & 3;
            int col = w * 32 + c * 16 + (lane & 15);
            int kb = s * 32 + (lane >> 4) * 8;
            short8v v;
#pragma unroll
            for (int j = 0; j < 8; j++)
                v[j] = (short)f2bf(Wr[(size_t)(kb + j) * E_DIM + col]);
            *(short8v*)(Wt + ((size_t)((((rel * 4 + w) * 4 + s) * 2 + c) * 64 + lane)) * 8) = v;
        }
    } else if (b < 18 + hblocks) {
        long i = (long)(b - 18) * 256 + tid;
        if (i >= total8) return;
        const float4* src = (const float4*)(H + i * 8);
        float4 a = src[0], bb = src[1];
        short8v o;
        o[0] = (short)f2bf(a.x); o[1] = (short)f2bf(a.y);
        o[2] = (short)f2bf(a.z); o[3] = (short)f2bf(a.w);
        o[4] = (short)f2bf(bb.x); o[5] = (short)f2bf(bb.y);
        o[6] = (short)f2bf(bb.z); o[7] = (short)f2bf(bb.w);
        *(short8v*)(Hbf + i * 8) = o;
    } else {
        const int c = b - 18 - hblocks;
        const int oct = c & 7;
        const int slice = c >> 3;
        const int lo = (int)(((long long)oct * Nn) >> 3);
        const int hi = (int)(((long long)(oct + 1) * Nn) >> 3);
        for (int e = slice * 256 + tid; e < ne; e += NSLICE * 256) {
            int t = etype[e], s = esrc[e], d = edst[e];
            if (d >= lo && d < hi) atomicAdd(&cnt[d * R_REL + t], 1);
            if (s >= lo && s < hi) atomicAdd(&cnt[(Nn + s) * R_REL + t], 1);
        }
    }
}

// Hierarchical scan, 3 kernels (r5-validated).
__global__ __launch_bounds__(256) void k_scan_part(
    const int* __restrict__ cnt, int* __restrict__ loc,
    int* __restrict__ bsum, int n2)
{
    __shared__ int sh[256];
    const int tid = threadIdx.x;
    const int i0 = blockIdx.x * SCB + tid * 4;
    int v0 = 0, v1 = 0, v2 = 0, v3 = 0;
    if (i0 + 3 < n2) {
        int4 v = *(const int4*)(cnt + i0);
        v0 = v.x; v1 = v.y; v2 = v.z; v3 = v.w;
    } else {
        if (i0 + 0 < n2) v0 = cnt[i0 + 0];
        if (i0 + 1 < n2) v1 = cnt[i0 + 1];
        if (i0 + 2 < n2) v2 = cnt[i0 + 2];
        if (i0 + 3 < n2) v3 = cnt[i0 + 3];
    }
    int t = v0 + v1 + v2 + v3;
    sh[tid] = t;
    __syncthreads();
    for (int o = 1; o < 256; o <<= 1) {
        int x = (tid >= o) ? sh[tid - o] : 0;
        __syncthreads();
        sh[tid] += x;
        __syncthreads();
    }
    int excl = sh[tid] - t;
    if (tid == 255) bsum[blockIdx.x] = sh[255];
    int p0 = excl, p1 = p0 + v0, p2 = p1 + v1, p3 = p2 + v2;
    if (i0 + 3 < n2) {
        *(int4*)(loc + i0) = make_int4(p0, p1, p2, p3);
    } else {
        if (i0 + 0 < n2) loc[i0 + 0] = p0;
        if (i0 + 1 < n2) loc[i0 + 1] = p1;
        if (i0 + 2 < n2) loc[i0 + 2] = p2;
        if (i0 + 3 < n2) loc[i0 + 3] = p3;
    }
}

__global__ __launch_bounds__(256) void k_scan_mid(int* __restrict__ bsum, int nb)
{
    __shared__ int sh[256];
    __shared__ int carry;
    const int tid = threadIdx.x;
    if (tid == 0) carry = 0;
    __syncthreads();
    for (int base = 0; base < nb; base += 256) {
        int i = base + tid;
        int v = (i < nb) ? bsum[i] : 0;
        sh[tid] = v;
        __syncthreads();
        for (int o = 1; o < 256; o <<= 1) {
            int x = (tid >= o) ? sh[tid - o] : 0;
            __syncthreads();
            sh[tid] += x;
            __syncthreads();
        }
        int excl = sh[tid] - v + carry;
        int total = sh[255];
        if (i < nb) bsum[i] = excl;
        __syncthreads();
        if (tid == 0) carry += total;
        __syncthreads();
    }
}

__global__ __launch_bounds__(256) void k_scan_apply(
    const int* __restrict__ loc, const int* __restrict__ bsum,
    int* __restrict__ off, int* __restrict__ cursor, int n2)
{
    const int add = bsum[blockIdx.x];
    const int i0 = blockIdx.x * SCB + threadIdx.x * 4;
    if (i0 + 3 < n2) {
        int4 v = *(const int4*)(loc + i0);
        v.x += add; v.y += add; v.z += add; v.w += add;
        *(int4*)(off + i0) = v;
        *(int4*)(cursor + i0) = v;
    } else {
#pragma unroll
        for (int j = 0; j < 4; j++)
            if (i0 + j < n2) {
                int v = loc[i0 + j] + add;
                off[i0 + j] = v;
                cursor[i0 + j] = v;
            }
    }
}

// rec = (t<<20) | otherNode, via (node,t) cursor -> type-grouped per node.
__global__ __launch_bounds__(256) void k_fill8(
    const int* __restrict__ esrc, const int* __restrict__ edst,
    const int* __restrict__ etype, int* __restrict__ cursor,
    unsigned* __restrict__ rec, int ne, int Nn)
{
    const int oct = blockIdx.x & 7;
    const int slice = blockIdx.x >> 3;
    const int lo = (int)(((long long)oct * Nn) >> 3);
    const int hi = (int)(((long long)(oct + 1) * Nn) >> 3);
    for (int e = slice * 256 + threadIdx.x; e < ne; e += NSLICE * 256) {
        int t = etype[e], s = esrc[e], d = edst[e];
        if (d >= lo && d < hi) {
            int p = atomicAdd(&cursor[d * R_REL + t], 1);
            rec[p] = ((unsigned)t << 20) | (unsigned)s;   // fwd msg into d
        }
        if (s >= lo && s < hi) {
            int p2 = atomicAdd(&cursor[(Nn + s) * R_REL + t], 1);
            rec[p2] = ((unsigned)t << 20) | (unsigned)d;  // bwd msg into s
        }
    }
}

// Fused aggregate+GEMM, K split in 3 type-chunks, PERSISTENT blocks.
// 2048 blocks x 4 waves, LDS ~13.8KB -> 8 blocks/CU; grid-stride over
// tiles removes the 3.05-round tail that capped r14 at 78% occupancy.
// Per tile, per dir: prefetch 9 type-bounds + degS; per chunk: zero own
// Mt rows; group g streams node w*4+g's records of types [3c,3c+3)
// (4-deep predicated, short8/lane); bf16 LDS RMW; barrier; MFMA
// acc += Mt_chunk @ W[dir,chunk] (swapped operands); barrier.
// Epilogue per tile: + deg_t*b_t both dirs, fp32 out store; barrier.
__global__ __launch_bounds__(256, 8) void fused_rgcn(
    const unsigned short* __restrict__ Hbf, const unsigned short* __restrict__ Wt,
    const float* __restrict__ B18,
    const int* __restrict__ off3, const int* __restrict__ cur3,
    const unsigned* __restrict__ rec,
    float* __restrict__ out, int Nn, int ntiles)
{
    __shared__ __align__(16) unsigned short Mt[TN][MT_P2];
    __shared__ float degS[2][TN][R_REL];

    const int tid = threadIdx.x;
    const int lane = tid & 63;
    const int w = tid >> 6;             // wave id; col slice w*32..w*32+31
    const int lr = lane & 15;
    const int lg = lane >> 4;
    const int grp = lg;                 // node-in-wave (aggregation role)
    const int gl = lr;                  // channel sub-lane: ch gl*8..gl*8+7
    const short8v z8 = (short8v){0, 0, 0, 0, 0, 0, 0, 0};
    const short8v* wt8 = (const short8v*)Wt;

#define RMW(rk, vk, tbase)                                                    \
    {                                                                         \
        int _tl = (int)((rk) >> 20) - (tbase);                                \
        unsigned short* _mp = &Mt[w * 4 + grp][_tl * E_DIM + gl * 8];         \
        short8v _m = *(short8v*)_mp;                                          \
        _Pragma("unroll")                                                     \
        for (int _c = 0; _c < 8; _c++) {                                      \
            float _f = bf2f((unsigned short)_m[_c]) +                         \
                       bf2f((unsigned short)(vk)[_c]);                        \
            _m[_c] = (short)f2bf(_f);                                         \
        }                                                                     \
        *(short8v*)_mp = _m;                                                  \
    }

    for (int tile = blockIdx.x; tile < ntiles; tile += gridDim.x) {
        const int n0 = tile * TN;

        f32x4 acc[2];
        acc[0] = (f32x4){0.f, 0.f, 0.f, 0.f};
        acc[1] = (f32x4){0.f, 0.f, 0.f, 0.f};

#pragma unroll 1
        for (int dir = 0; dir < 2; dir++) {
            // Prefetch bounds: lane = jj*16 + tt (jj = node, tt = type).
            const int jj = lg, tt = lr;
            const int gnode_j = n0 + w * 4 + jj;
            int blo = 0x7F000000, bhi = 0x7F000000;
            if (gnode_j < Nn && tt < R_REL) {
                size_t sb = ((size_t)(dir ? (Nn + gnode_j) : gnode_j)) * R_REL + tt;
                blo = off3[sb];
                bhi = cur3[sb];
                degS[dir][w * 4 + jj][tt] = (float)(bhi - blo);
            }

#pragma unroll 1
            for (int ch = 0; ch < 3; ch++) {
                const int tbase = ch * TCH;
                // Zero this wave's Mt rows (384 used ushorts = 48 short8/row).
#pragma unroll
                for (int rr = 0; rr < 4; rr++) {
                    if (lane < 48)
                        *(short8v*)(&Mt[w * 4 + rr][(size_t)lane * 8]) = z8;
                }

                // Per-group record range for this chunk.
                const int st_g = __shfl(blo, grp * 16 + tbase);
                const int en_g = __shfl(bhi, grp * 16 + tbase + TCH - 1);

                int ii = st_g;
                while (__any(ii < en_g)) {
                    bool a0 = ii + 0 < en_g;
                    bool a1 = ii + 1 < en_g;
                    bool a2 = ii + 2 < en_g;
                    bool a3 = ii + 3 < en_g;
                    unsigned r0 = 0, r1 = 0, r2 = 0, r3 = 0;
                    if (a0) r0 = rec[ii + 0];
                    if (a1) r1 = rec[ii + 1];
                    if (a2) r2 = rec[ii + 2];
                    if (a3) r3 = rec[ii + 3];
                    short8v v0 = z8, v1 = z8, v2 = z8, v3 = z8;
                    if (a0) v0 = *(const short8v*)(Hbf + (size_t)(r0 & 0xFFFFF) * E_DIM + gl * 8);
                    if (a1) v1 = *(const short8v*)(Hbf + (size_t)(r1 & 0xFFFFF) * E_DIM + gl * 8);
                    if (a2) v2 = *(const short8v*)(Hbf + (size_t)(r2 & 0xFFFFF) * E_DIM + gl * 8);
                    if (a3) v3 = *(const short8v*)(Hbf + (size_t)(r3 & 0xFFFFF) * E_DIM + gl * 8);
                    if (a0) RMW(r0, v0, tbase);
                    if (a1) RMW(r1, v1, tbase);
                    if (a2) RMW(r2, v2, tbase);
                    if (a3) RMW(r3, v3, tbase);
                    ii += 4;
                }
                __syncthreads();

                // ---- GEMM: acc += Mt_chunk @ W[dir, chunk types] ----
#pragma unroll
                for (int q = 0; q < TCH; q++) {
                    const int rel = dir * R_REL + tbase + q;
#pragma unroll
                    for (int s = 0; s < 4; s++) {
                        short8v b0 = wt8[(size_t)((((rel * 4 + w) * 4 + s) * 2 + 0) * 64) + lane];
                        short8v b1 = wt8[(size_t)((((rel * 4 + w) * 4 + s) * 2 + 1) * 64) + lane];
                        short8v a = *(const short8v*)(&Mt[lr][q * E_DIM + s * 32 + lg * 8]);
                        acc[0] = __builtin_amdgcn_mfma_f32_16x16x32_bf16(b0, a, acc[0], 0, 0, 0);
                        acc[1] = __builtin_amdgcn_mfma_f32_16x16x32_bf16(b1, a, acc[1], 0, 0, 0);
                    }
                }
                __syncthreads();   // before next chunk overwrites Mt
            }
        }

        // ---- epilogue: bias (deg_t * b_t) + store (guarded) ----
        const int gnode = n0 + lr;
        if (gnode < Nn) {
#pragma unroll 1
            for (int dir = 0; dir < 2; dir++) {
#pragma unroll 1
                for (int t = 0; t < R_REL; t++) {
                    float dg = degS[dir][lr][t];
                    if (dg != 0.f) {
                        const float* brow = B18 + (size_t)(dir * R_REL + t) * E_DIM + w * 32 + lg * 4;
                        float4 b0 = *(const float4*)(brow);
                        float4 b1 = *(const float4*)(brow + 16);
                        acc[0][0] += dg * b0.x; acc[0][1] += dg * b0.y;
                        acc[0][2] += dg * b0.z; acc[0][3] += dg * b0.w;
                        acc[1][0] += dg * b1.x; acc[1][1] += dg * b1.y;
                        acc[1][2] += dg * b1.z; acc[1][3] += dg * b1.w;
                    }
                }
            }
            float* po = out + (size_t)gnode * E_DIM + w * 32 + lg * 4;
            *(float4*)po = make_float4(acc[0][0], acc[0][1], acc[0][2], acc[0][3]);
            *(float4*)(po + 16) = make_float4(acc[1][0], acc[1][1], acc[1][2], acc[1][3]);
        }
        __syncthreads();   // degS/Mt reuse by next tile
    }
#undef RMW
}

// ---------- zero-workspace fallback (round-1, validated) ----------

__global__ __launch_bounds__(128) void direct_edge(
    const int* __restrict__ esrc, const int* __restrict__ edst,
    const int* __restrict__ etype,
    const float* __restrict__ H, const float* __restrict__ W2,
    const float* __restrict__ B2, float* __restrict__ out, int ne)
{
    __shared__ float hs[E_DIM];
    __shared__ float hd[E_DIM];
    int e = blockIdx.x;
    if (e >= ne) return;
    int t = etype[e], s = esrc[e], d = edst[e];
    int c = threadIdx.x;
    hs[c] = H[(size_t)s * E_DIM + c];
    hd[c] = H[(size_t)d * E_DIM + c];
    __syncthreads();
    const float* Wf = W2 + (size_t)t * E_DIM * E_DIM;
    const float* Wb = W2 + (size_t)(t + R_REL) * E_DIM * E_DIM;
    float accf = B2[(size_t)t * E_DIM + c];
    float accb = B2[(size_t)(t + R_REL) * E_DIM + c];
#pragma unroll 8
    for (int k = 0; k < E_DIM; k++) {
        accf += hs[k] * Wf[(size_t)k * E_DIM + c];
        accb += hd[k] * Wb[(size_t)k * E_DIM + c];
    }
    atomicAdd(&out[(size_t)d * E_DIM + c], accf);
    atomicAdd(&out[(size_t)s * E_DIM + c], accb);
}

extern "C" void kernel_launch(void* const* d_in, const int* in_sizes, int n_in,
                              void* d_out, int out_size, void* d_ws, size_t ws_size,
                              hipStream_t stream) {
    const int* edge_index = (const int*)d_in[0];   // [2][NE]
    const int* edge_type  = (const int*)d_in[1];   // [NE]
    const float* emb      = (const float*)d_in[2]; // [N][128]
    const float* weights  = (const float*)d_in[3]; // [L][18][128][128]
    const float* biases   = (const float*)d_in[4]; // [L][18][128]
    float* out = (float*)d_out;

    const int NE = in_sizes[1];
    const int Nn = in_sizes[2] / E_DIM;
    const int L  = in_sizes[3] / (2 * R_REL * E_DIM * E_DIM);

    const float* W2 = weights + (size_t)(L - 1) * 2 * R_REL * E_DIM * E_DIM;
    const float* B2 = biases  + (size_t)(L - 1) * 2 * R_REL * E_DIM;

    const int* esrc = edge_index;
    const int* edst = edge_index + NE;

    const int n3 = 2 * Nn * R_REL;                 // (node,dir,type) segments
    const int nb3 = (n3 + SCB - 1) / SCB;

    auto al = [](size_t x) { return (x + 255) & ~(size_t)255; };
    const size_t hbfBytes = al((size_t)Nn * E_DIM * 2);
    const size_t wtBytes  = al((size_t)2 * R_REL * E_DIM * E_DIM * 2);
    const size_t offBytes = al((size_t)n3 * 4);
    const size_t curBytes = al((size_t)n3 * 4);
    const size_t recBytes = al((size_t)2 * NE * 4);
    const size_t bsBytes  = al((size_t)nb3 * 4);
    const size_t need = hbfBytes + wtBytes + offBytes + curBytes + recBytes + bsBytes;

    if (ws_size >= need && Nn < (1 << 20)) {
        char* p = (char*)d_ws;
        unsigned short* Hbf = (unsigned short*)p;        p += hbfBytes;
        unsigned short* Wt  = (unsigned short*)p;        p += wtBytes;
        int* off3           = (int*)p;                   p += offBytes;
        int* cur3           = (int*)p;                   p += curBytes;
        unsigned* rec       = (unsigned*)p;              p += recBytes;
        int* bsum           = (int*)p;

        const long total8 = (long)Nn * (E_DIM / 8);
        const int hblocks = (int)((total8 + 255) / 256);

        hipMemsetAsync(off3, 0, (size_t)n3 * 4, stream);
        prep_count<<<18 + hblocks + 8 * NSLICE, 256, 0, stream>>>(
            emb, W2, esrc, edst, edge_type, Hbf, Wt, off3,
            total8, hblocks, NE, Nn);
        k_scan_part<<<nb3, 256, 0, stream>>>(off3, cur3, bsum, n3);
        k_scan_mid<<<1, 256, 0, stream>>>(bsum, nb3);
        k_scan_apply<<<nb3, 256, 0, stream>>>(cur3, bsum, off3, cur3, n3);
        k_fill8<<<8 * NSLICE, 256, 0, stream>>>(esrc, edst, edge_type,
                                                cur3, rec, NE, Nn);

        const int ntiles = (Nn + TN - 1) / TN;
        const int pgrid = (ntiles < 2048) ? ntiles : 2048;   // 8 blk/CU x 256 CU
        fused_rgcn<<<pgrid, 256, 0, stream>>>(
            Hbf, Wt, B2, off3, cur3, rec, out, Nn, ntiles);
        return;
    }

    // Fallback: direct per-edge GEMV with atomics.
    hipMemsetAsync(d_out, 0, (size_t)Nn * E_DIM * sizeof(float), stream);
    direct_edge<<<NE, 128, 0, stream>>>(esrc, edst, edge_type, emb, W2, B2, out, NE);
}

// Round 17
// 338.661 us; speedup vs baseline: 1.1025x; 1.0279x over previous
//
#include <hip/hip_runtime.h>
#include <hip/hip_bf16.h>

// RGCN encoder: N=100000, E=128, R=9, L=3, NE=640000. Only the LAST layer
// matters (reference resets hidden=embeddings each layer).
//   out[n] = sum_{e:dst=n}(W_t h[src]+b_t) + sum_{e:src=n}(W_{t+9} h[dst]+b_{t+9})
// AGGREGATE-FIRST (linearity): out[d] = sum_t W_t * M_t[d] + deg_t(d)*b_t.
// Round-17: FP16 pipeline. r14/r16's bf16 LDS RMW cost ~40 VALU/record
// (unpack+add+repack). With Hbf/Wt/Mt in fp16 the RMW is a single half8
// vector add -> 4 v_pk_add_f16 (packed math), LDS size unchanged (13.8KB,
// 8 blk/CU), MFMA switches to 16x16x32_f16 (same rate, same layout).
// fp16 also has MORE mantissa than bf16 for these O(1..150) values.
// CSR, chunked streaming (r14), persistent grid (r16), epilogue: unchanged.

#define E_DIM 128
#define R_REL 9
#define TN 16        // nodes per fused block
#define TCH 3        // types per chunk
#define MT_P2 392    // Mt pitch in halves (384 used + 8 pad)
#define SCB 1024     // elements per scan block
#define NSLICE 96    // edge slices per octant in count/fill

typedef __attribute__((ext_vector_type(8))) _Float16 half8v;
typedef __attribute__((ext_vector_type(4))) float f32x4;

// ---------- fast path ----------

// Fused prep + count: blocks [0,18) swizzle W into MFMA fragment order
// (fp32 -> fp16); [18, 18+hblocks) convert H fp32 -> fp16; rest:
// octant-partitioned count over (node,dir,type) segments.
__global__ __launch_bounds__(256) void prep_count(
    const float* __restrict__ H, const float* __restrict__ W18,
    const int* __restrict__ esrc, const int* __restrict__ edst,
    const int* __restrict__ etype,
    _Float16* __restrict__ Hbf, _Float16* __restrict__ Wt,
    int* __restrict__ cnt, long total8, int hblocks, int ne, int Nn)
{
    const int tid = threadIdx.x;
    const int b = blockIdx.x;
    if (b < 18) {
        const int rel = b;
        const float* __restrict__ Wr = W18 + (size_t)rel * E_DIM * E_DIM;
#pragma unroll
        for (int k = 0; k < 8; k++) {
            int f = tid + k * 256;            // 0..2047
            int lane = f & 63;
            int c = (f >> 6) & 1;
            int s = (f >> 7) & 3;
            int w = (f >> 9) & 3;
            int col = w * 32 + c * 16 + (lane & 15);
            int kb = s * 32 + (lane >> 4) * 8;
            half8v v;
#pragma unroll
            for (int j = 0; j < 8; j++)
                v[j] = (_Float16)(Wr[(size_t)(kb + j) * E_DIM + col]);
            *(half8v*)(Wt + ((size_t)((((rel * 4 + w) * 4 + s) * 2 + c) * 64 + lane)) * 8) = v;
        }
    } else if (b < 18 + hblocks) {
        long i = (long)(b - 18) * 256 + tid;
        if (i >= total8) return;
        const float4* src = (const float4*)(H + i * 8);
        float4 a = src[0], bb = src[1];
        half8v o;
        o[0] = (_Float16)a.x;  o[1] = (_Float16)a.y;
        o[2] = (_Float16)a.z;  o[3] = (_Float16)a.w;
        o[4] = (_Float16)bb.x; o[5] = (_Float16)bb.y;
        o[6] = (_Float16)bb.z; o[7] = (_Float16)bb.w;
        *(half8v*)(Hbf + i * 8) = o;
    } else {
        const int c = b - 18 - hblocks;
        const int oct = c & 7;
        const int slice = c >> 3;
        const int lo = (int)(((long long)oct * Nn) >> 3);
        const int hi = (int)(((long long)(oct + 1) * Nn) >> 3);
        for (int e = slice * 256 + tid; e < ne; e += NSLICE * 256) {
            int t = etype[e], s = esrc[e], d = edst[e];
            if (d >= lo && d < hi) atomicAdd(&cnt[d * R_REL + t], 1);
            if (s >= lo && s < hi) atomicAdd(&cnt[(Nn + s) * R_REL + t], 1);
        }
    }
}

// Hierarchical scan, 3 kernels (r5-validated).
__global__ __launch_bounds__(256) void k_scan_part(
    const int* __restrict__ cnt, int* __restrict__ loc,
    int* __restrict__ bsum, int n2)
{
    __shared__ int sh[256];
    const int tid = threadIdx.x;
    const int i0 = blockIdx.x * SCB + tid * 4;
    int v0 = 0, v1 = 0, v2 = 0, v3 = 0;
    if (i0 + 3 < n2) {
        int4 v = *(const int4*)(cnt + i0);
        v0 = v.x; v1 = v.y; v2 = v.z; v3 = v.w;
    } else {
        if (i0 + 0 < n2) v0 = cnt[i0 + 0];
        if (i0 + 1 < n2) v1 = cnt[i0 + 1];
        if (i0 + 2 < n2) v2 = cnt[i0 + 2];
        if (i0 + 3 < n2) v3 = cnt[i0 + 3];
    }
    int t = v0 + v1 + v2 + v3;
    sh[tid] = t;
    __syncthreads();
    for (int o = 1; o < 256; o <<= 1) {
        int x = (tid >= o) ? sh[tid - o] : 0;
        __syncthreads();
        sh[tid] += x;
        __syncthreads();
    }
    int excl = sh[tid] - t;
    if (tid == 255) bsum[blockIdx.x] = sh[255];
    int p0 = excl, p1 = p0 + v0, p2 = p1 + v1, p3 = p2 + v2;
    if (i0 + 3 < n2) {
        *(int4*)(loc + i0) = make_int4(p0, p1, p2, p3);
    } else {
        if (i0 + 0 < n2) loc[i0 + 0] = p0;
        if (i0 + 1 < n2) loc[i0 + 1] = p1;
        if (i0 + 2 < n2) loc[i0 + 2] = p2;
        if (i0 + 3 < n2) loc[i0 + 3] = p3;
    }
}

__global__ __launch_bounds__(256) void k_scan_mid(int* __restrict__ bsum, int nb)
{
    __shared__ int sh[256];
    __shared__ int carry;
    const int tid = threadIdx.x;
    if (tid == 0) carry = 0;
    __syncthreads();
    for (int base = 0; base < nb; base += 256) {
        int i = base + tid;
        int v = (i < nb) ? bsum[i] : 0;
        sh[tid] = v;
        __syncthreads();
        for (int o = 1; o < 256; o <<= 1) {
            int x = (tid >= o) ? sh[tid - o] : 0;
            __syncthreads();
            sh[tid] += x;
            __syncthreads();
        }
        int excl = sh[tid] - v + carry;
        int total = sh[255];
        if (i < nb) bsum[i] = excl;
        __syncthreads();
        if (tid == 0) carry += total;
        __syncthreads();
    }
}

__global__ __launch_bounds__(256) void k_scan_apply(
    const int* __restrict__ loc, const int* __restrict__ bsum,
    int* __restrict__ off, int* __restrict__ cursor, int n2)
{
    const int add = bsum[blockIdx.x];
    const int i0 = blockIdx.x * SCB + threadIdx.x * 4;
    if (i0 + 3 < n2) {
        int4 v = *(const int4*)(loc + i0);
        v.x += add; v.y += add; v.z += add; v.w += add;
        *(int4*)(off + i0) = v;
        *(int4*)(cursor + i0) = v;
    } else {
#pragma unroll
        for (int j = 0; j < 4; j++)
            if (i0 + j < n2) {
                int v = loc[i0 + j] + add;
                off[i0 + j] = v;
                cursor[i0 + j] = v;
            }
    }
}

// rec = (t<<20) | otherNode, via (node,t) cursor -> type-grouped per node.
__global__ __launch_bounds__(256) void k_fill8(
    const int* __restrict__ esrc, const int* __restrict__ edst,
    const int* __restrict__ etype, int* __restrict__ cursor,
    unsigned* __restrict__ rec, int ne, int Nn)
{
    const int oct = blockIdx.x & 7;
    const int slice = blockIdx.x >> 3;
    const int lo = (int)(((long long)oct * Nn) >> 3);
    const int hi = (int)(((long long)(oct + 1) * Nn) >> 3);
    for (int e = slice * 256 + threadIdx.x; e < ne; e += NSLICE * 256) {
        int t = etype[e], s = esrc[e], d = edst[e];
        if (d >= lo && d < hi) {
            int p = atomicAdd(&cursor[d * R_REL + t], 1);
            rec[p] = ((unsigned)t << 20) | (unsigned)s;   // fwd msg into d
        }
        if (s >= lo && s < hi) {
            int p2 = atomicAdd(&cursor[(Nn + s) * R_REL + t], 1);
            rec[p2] = ((unsigned)t << 20) | (unsigned)d;  // bwd msg into s
        }
    }
}

// Fused aggregate+GEMM, fp16, 3 type-chunks, persistent blocks.
// 2048 blocks x 4 waves, LDS ~13.8KB -> 8 blk/CU. Per tile, per dir:
// prefetch 9 type-bounds + degS; per chunk: zero own Mt rows; group g
// streams node w*4+g's records of types [3c,3c+3) (4-deep predicated,
// half8/lane); RMW = single half8 vector add (4x v_pk_add_f16); barrier;
// MFMA f16 acc += Mt_chunk @ W[dir,chunk] (swapped operands); barrier.
// Epilogue per tile: + deg_t*b_t both dirs (fp32), fp32 out store.
__global__ __launch_bounds__(256, 8) void fused_rgcn(
    const _Float16* __restrict__ Hbf, const _Float16* __restrict__ Wt,
    const float* __restrict__ B18,
    const int* __restrict__ off3, const int* __restrict__ cur3,
    const unsigned* __restrict__ rec,
    float* __restrict__ out, int Nn, int ntiles)
{
    __shared__ __align__(16) _Float16 Mt[TN][MT_P2];
    __shared__ float degS[2][TN][R_REL];

    const int tid = threadIdx.x;
    const int lane = tid & 63;
    const int w = tid >> 6;             // wave id; col slice w*32..w*32+31
    const int lr = lane & 15;
    const int lg = lane >> 4;
    const int grp = lg;                 // node-in-wave (aggregation role)
    const int gl = lr;                  // channel sub-lane: ch gl*8..gl*8+7
    const half8v z8 = (half8v){0, 0, 0, 0, 0, 0, 0, 0};
    const half8v* wt8 = (const half8v*)Wt;

#define RMW(rk, vk, tbase)                                                    \
    {                                                                         \
        int _tl = (int)((rk) >> 20) - (tbase);                                \
        half8v* _mp = (half8v*)(&Mt[w * 4 + grp][_tl * E_DIM + gl * 8]);      \
        *_mp = *_mp + (vk);                                                   \
    }

    for (int tile = blockIdx.x; tile < ntiles; tile += gridDim.x) {
        const int n0 = tile * TN;

        f32x4 acc[2];
        acc[0] = (f32x4){0.f, 0.f, 0.f, 0.f};
        acc[1] = (f32x4){0.f, 0.f, 0.f, 0.f};

#pragma unroll 1
        for (int dir = 0; dir < 2; dir++) {
            // Prefetch bounds: lane = jj*16 + tt (jj = node, tt = type).
            const int jj = lg, tt = lr;
            const int gnode_j = n0 + w * 4 + jj;
            int blo = 0x7F000000, bhi = 0x7F000000;
            if (gnode_j < Nn && tt < R_REL) {
                size_t sb = ((size_t)(dir ? (Nn + gnode_j) : gnode_j)) * R_REL + tt;
                blo = off3[sb];
                bhi = cur3[sb];
                degS[dir][w * 4 + jj][tt] = (float)(bhi - blo);
            }

#pragma unroll 1
            for (int ch = 0; ch < 3; ch++) {
                const int tbase = ch * TCH;
                // Zero this wave's Mt rows (384 used halves = 48 half8/row).
#pragma unroll
                for (int rr = 0; rr < 4; rr++) {
                    if (lane < 48)
                        *(half8v*)(&Mt[w * 4 + rr][(size_t)lane * 8]) = z8;
                }

                // Per-group record range for this chunk.
                const int st_g = __shfl(blo, grp * 16 + tbase);
                const int en_g = __shfl(bhi, grp * 16 + tbase + TCH - 1);

                int ii = st_g;
                while (__any(ii < en_g)) {
                    bool a0 = ii + 0 < en_g;
                    bool a1 = ii + 1 < en_g;
                    bool a2 = ii + 2 < en_g;
                    bool a3 = ii + 3 < en_g;
                    unsigned r0 = 0, r1 = 0, r2 = 0, r3 = 0;
                    if (a0) r0 = rec[ii + 0];
                    if (a1) r1 = rec[ii + 1];
                    if (a2) r2 = rec[ii + 2];
                    if (a3) r3 = rec[ii + 3];
                    half8v v0 = z8, v1 = z8, v2 = z8, v3 = z8;
                    if (a0) v0 = *(const half8v*)(Hbf + (size_t)(r0 & 0xFFFFF) * E_DIM + gl * 8);
                    if (a1) v1 = *(const half8v*)(Hbf + (size_t)(r1 & 0xFFFFF) * E_DIM + gl * 8);
                    if (a2) v2 = *(const half8v*)(Hbf + (size_t)(r2 & 0xFFFFF) * E_DIM + gl * 8);
                    if (a3) v3 = *(const half8v*)(Hbf + (size_t)(r3 & 0xFFFFF) * E_DIM + gl * 8);
                    if (a0) RMW(r0, v0, tbase);
                    if (a1) RMW(r1, v1, tbase);
                    if (a2) RMW(r2, v2, tbase);
                    if (a3) RMW(r3, v3, tbase);
                    ii += 4;
                }
                __syncthreads();

                // ---- GEMM: acc += Mt_chunk @ W[dir, chunk types] ----
#pragma unroll
                for (int q = 0; q < TCH; q++) {
                    const int rel = dir * R_REL + tbase + q;
#pragma unroll
                    for (int s = 0; s < 4; s++) {
                        half8v b0 = wt8[(size_t)((((rel * 4 + w) * 4 + s) * 2 + 0) * 64) + lane];
                        half8v b1 = wt8[(size_t)((((rel * 4 + w) * 4 + s) * 2 + 1) * 64) + lane];
                        half8v a = *(const half8v*)(&Mt[lr][q * E_DIM + s * 32 + lg * 8]);
                        acc[0] = __builtin_amdgcn_mfma_f32_16x16x32_f16(b0, a, acc[0], 0, 0, 0);
                        acc[1] = __builtin_amdgcn_mfma_f32_16x16x32_f16(b1, a, acc[1], 0, 0, 0);
                    }
                }
                __syncthreads();   // before next chunk overwrites Mt
            }
        }

        // ---- epilogue: bias (deg_t * b_t) + store (guarded) ----
        const int gnode = n0 + lr;
        if (gnode < Nn) {
#pragma unroll 1
            for (int dir = 0; dir < 2; dir++) {
#pragma unroll 1
                for (int t = 0; t < R_REL; t++) {
                    float dg = degS[dir][lr][t];
                    if (dg != 0.f) {
                        const float* brow = B18 + (size_t)(dir * R_REL + t) * E_DIM + w * 32 + lg * 4;
                        float4 b0 = *(const float4*)(brow);
                        float4 b1 = *(const float4*)(brow + 16);
                        acc[0][0] += dg * b0.x; acc[0][1] += dg * b0.y;
                        acc[0][2] += dg * b0.z; acc[0][3] += dg * b0.w;
                        acc[1][0] += dg * b1.x; acc[1][1] += dg * b1.y;
                        acc[1][2] += dg * b1.z; acc[1][3] += dg * b1.w;
                    }
                }
            }
            float* po = out + (size_t)gnode * E_DIM + w * 32 + lg * 4;
            *(float4*)po = make_float4(acc[0][0], acc[0][1], acc[0][2], acc[0][3]);
            *(float4*)(po + 16) = make_float4(acc[1][0], acc[1][1], acc[1][2], acc[1][3]);
        }
        __syncthreads();   // degS/Mt reuse by next tile
    }
#undef RMW
}

// ---------- zero-workspace fallback (round-1, validated) ----------

__global__ __launch_bounds__(128) void direct_edge(
    const int* __restrict__ esrc, const int* __restrict__ edst,
    const int* __restrict__ etype,
    const float* __restrict__ H, const float* __restrict__ W2,
    const float* __restrict__ B2, float* __restrict__ out, int ne)
{
    __shared__ float hs[E_DIM];
    __shared__ float hd[E_DIM];
    int e = blockIdx.x;
    if (e >= ne) return;
    int t = etype[e], s = esrc[e], d = edst[e];
    int c = threadIdx.x;
    hs[c] = H[(size_t)s * E_DIM + c];
    hd[c] = H[(size_t)d * E_DIM + c];
    __syncthreads();
    const float* Wf = W2 + (size_t)t * E_DIM * E_DIM;
    const float* Wb = W2 + (size_t)(t + R_REL) * E_DIM * E_DIM;
    float accf = B2[(size_t)t * E_DIM + c];
    float accb = B2[(size_t)(t + R_REL) * E_DIM + c];
#pragma unroll 8
    for (int k = 0; k < E_DIM; k++) {
        accf += hs[k] * Wf[(size_t)k * E_DIM + c];
        accb += hd[k] * Wb[(size_t)k * E_DIM + c];
    }
    atomicAdd(&out[(size_t)d * E_DIM + c], accf);
    atomicAdd(&out[(size_t)s * E_DIM + c], accb);
}

extern "C" void kernel_launch(void* const* d_in, const int* in_sizes, int n_in,
                              void* d_out, int out_size, void* d_ws, size_t ws_size,
                              hipStream_t stream) {
    const int* edge_index = (const int*)d_in[0];   // [2][NE]
    const int* edge_type  = (const int*)d_in[1];   // [NE]
    const float* emb      = (const float*)d_in[2]; // [N][128]
    const float* weights  = (const float*)d_in[3]; // [L][18][128][128]
    const float* biases   = (const float*)d_in[4]; // [L][18][128]
    float* out = (float*)d_out;

    const int NE = in_sizes[1];
    const int Nn = in_sizes[2] / E_DIM;
    const int L  = in_sizes[3] / (2 * R_REL * E_DIM * E_DIM);

    const float* W2 = weights + (size_t)(L - 1) * 2 * R_REL * E_DIM * E_DIM;
    const float* B2 = biases  + (size_t)(L - 1) * 2 * R_REL * E_DIM;

    const int* esrc = edge_index;
    const int* edst = edge_index + NE;

    const int n3 = 2 * Nn * R_REL;                 // (node,dir,type) segments
    const int nb3 = (n3 + SCB - 1) / SCB;

    auto al = [](size_t x) { return (x + 255) & ~(size_t)255; };
    const size_t hbfBytes = al((size_t)Nn * E_DIM * 2);
    const size_t wtBytes  = al((size_t)2 * R_REL * E_DIM * E_DIM * 2);
    const size_t offBytes = al((size_t)n3 * 4);
    const size_t curBytes = al((size_t)n3 * 4);
    const size_t recBytes = al((size_t)2 * NE * 4);
    const size_t bsBytes  = al((size_t)nb3 * 4);
    const size_t need = hbfBytes + wtBytes + offBytes + curBytes + recBytes + bsBytes;

    if (ws_size >= need && Nn < (1 << 20)) {
        char* p = (char*)d_ws;
        _Float16* Hbf = (_Float16*)p;                    p += hbfBytes;
        _Float16* Wt  = (_Float16*)p;                    p += wtBytes;
        int* off3           = (int*)p;                   p += offBytes;
        int* cur3           = (int*)p;                   p += curBytes;
        unsigned* rec       = (unsigned*)p;              p += recBytes;
        int* bsum           = (int*)p;

        const long total8 = (long)Nn * (E_DIM / 8);
        const int hblocks = (int)((total8 + 255) / 256);

        hipMemsetAsync(off3, 0, (size_t)n3 * 4, stream);
        prep_count<<<18 + hblocks + 8 * NSLICE, 256, 0, stream>>>(
            emb, W2, esrc, edst, edge_type, Hbf, Wt, off3,
            total8, hblocks, NE, Nn);
        k_scan_part<<<nb3, 256, 0, stream>>>(off3, cur3, bsum, n3);
        k_scan_mid<<<1, 256, 0, stream>>>(bsum, nb3);
        k_scan_apply<<<nb3, 256, 0, stream>>>(cur3, bsum, off3, cur3, n3);
        k_fill8<<<8 * NSLICE, 256, 0, stream>>>(esrc, edst, edge_type,
                                                cur3, rec, NE, Nn);

        const int ntiles = (Nn + TN - 1) / TN;
        const int pgrid = (ntiles < 2048) ? ntiles : 2048;   // 8 blk/CU x 256 CU
        fused_rgcn<<<pgrid, 256, 0, stream>>>(
            Hbf, Wt, B2, off3, cur3, rec, out, Nn, ntiles);
        return;
    }

    // Fallback: direct per-edge GEMV with atomics.
    hipMemsetAsync(d_out, 0, (size_t)Nn * E_DIM * sizeof(float), stream);
    direct_edge<<<NE, 128, 0, stream>>>(esrc, edst, edge_type, emb, W2, B2, out, NE);
}

// Round 18
// 337.143 us; speedup vs baseline: 1.1074x; 1.0045x over previous
//
#include <hip/hip_runtime.h>
#include <hip/hip_bf16.h>

// RGCN encoder: N=100000, E=128, R=9, L=3, NE=640000. Only the LAST layer
// matters (reference resets hidden=embeddings each layer).
//   out[n] = sum_{e:dst=n}(W_t h[src]+b_t) + sum_{e:src=n}(W_{t+9} h[dst]+b_{t+9})
// AGGREGATE-FIRST (linearity): out[d] = sum_t W_t * M_t[d] + deg_t(d)*b_t.
// Round-18: aggregation is LATENCY-bound (r17: fp16 RMW cut VALU 37->22.6%
// for only -11us). Occupancy law (r8/r12/r14): gather rate ~ resident waves.
// r17 had 12 barrier phases/tile and 2.1-record chunk segments. Now 2 chunks
// (types 0-4 / 5-8): Mt [16][648] fp16 = 21.9KB LDS -> 7 blk/CU = 87.5% occ
// cap, 8 phases/tile, segments 3.6/2.8 records (4-deep batches fill).
// CSR, fp16 RMW streaming, MFMA (runtime chunk len), epilogue: unchanged.

#define E_DIM 128
#define R_REL 9
#define TN 16        // nodes per fused block
#define MT_P 648     // Mt pitch in halves (5*128 used + 8 pad)
#define SCB 1024     // elements per scan block
#define NSLICE 96    // edge slices per octant in count/fill

typedef __attribute__((ext_vector_type(8))) _Float16 half8v;
typedef __attribute__((ext_vector_type(4))) float f32x4;

// ---------- fast path ----------

// Fused prep + count: blocks [0,18) swizzle W into MFMA fragment order
// (fp32 -> fp16); [18, 18+hblocks) convert H fp32 -> fp16; rest:
// octant-partitioned count over (node,dir,type) segments.
__global__ __launch_bounds__(256) void prep_count(
    const float* __restrict__ H, const float* __restrict__ W18,
    const int* __restrict__ esrc, const int* __restrict__ edst,
    const int* __restrict__ etype,
    _Float16* __restrict__ Hbf, _Float16* __restrict__ Wt,
    int* __restrict__ cnt, long total8, int hblocks, int ne, int Nn)
{
    const int tid = threadIdx.x;
    const int b = blockIdx.x;
    if (b < 18) {
        const int rel = b;
        const float* __restrict__ Wr = W18 + (size_t)rel * E_DIM * E_DIM;
#pragma unroll
        for (int k = 0; k < 8; k++) {
            int f = tid + k * 256;            // 0..2047
            int lane = f & 63;
            int c = (f >> 6) & 1;
            int s = (f >> 7) & 3;
            int w = (f >> 9) & 3;
            int col = w * 32 + c * 16 + (lane & 15);
            int kb = s * 32 + (lane >> 4) * 8;
            half8v v;
#pragma unroll
            for (int j = 0; j < 8; j++)
                v[j] = (_Float16)(Wr[(size_t)(kb + j) * E_DIM + col]);
            *(half8v*)(Wt + ((size_t)((((rel * 4 + w) * 4 + s) * 2 + c) * 64 + lane)) * 8) = v;
        }
    } else if (b < 18 + hblocks) {
        long i = (long)(b - 18) * 256 + tid;
        if (i >= total8) return;
        const float4* src = (const float4*)(H + i * 8);
        float4 a = src[0], bb = src[1];
        half8v o;
        o[0] = (_Float16)a.x;  o[1] = (_Float16)a.y;
        o[2] = (_Float16)a.z;  o[3] = (_Float16)a.w;
        o[4] = (_Float16)bb.x; o[5] = (_Float16)bb.y;
        o[6] = (_Float16)bb.z; o[7] = (_Float16)bb.w;
        *(half8v*)(Hbf + i * 8) = o;
    } else {
        const int c = b - 18 - hblocks;
        const int oct = c & 7;
        const int slice = c >> 3;
        const int lo = (int)(((long long)oct * Nn) >> 3);
        const int hi = (int)(((long long)(oct + 1) * Nn) >> 3);
        for (int e = slice * 256 + tid; e < ne; e += NSLICE * 256) {
            int t = etype[e], s = esrc[e], d = edst[e];
            if (d >= lo && d < hi) atomicAdd(&cnt[d * R_REL + t], 1);
            if (s >= lo && s < hi) atomicAdd(&cnt[(Nn + s) * R_REL + t], 1);
        }
    }
}

// Hierarchical scan, 3 kernels (r5-validated).
__global__ __launch_bounds__(256) void k_scan_part(
    const int* __restrict__ cnt, int* __restrict__ loc,
    int* __restrict__ bsum, int n2)
{
    __shared__ int sh[256];
    const int tid = threadIdx.x;
    const int i0 = blockIdx.x * SCB + tid * 4;
    int v0 = 0, v1 = 0, v2 = 0, v3 = 0;
    if (i0 + 3 < n2) {
        int4 v = *(const int4*)(cnt + i0);
        v0 = v.x; v1 = v.y; v2 = v.z; v3 = v.w;
    } else {
        if (i0 + 0 < n2) v0 = cnt[i0 + 0];
        if (i0 + 1 < n2) v1 = cnt[i0 + 1];
        if (i0 + 2 < n2) v2 = cnt[i0 + 2];
        if (i0 + 3 < n2) v3 = cnt[i0 + 3];
    }
    int t = v0 + v1 + v2 + v3;
    sh[tid] = t;
    __syncthreads();
    for (int o = 1; o < 256; o <<= 1) {
        int x = (tid >= o) ? sh[tid - o] : 0;
        __syncthreads();
        sh[tid] += x;
        __syncthreads();
    }
    int excl = sh[tid] - t;
    if (tid == 255) bsum[blockIdx.x] = sh[255];
    int p0 = excl, p1 = p0 + v0, p2 = p1 + v1, p3 = p2 + v2;
    if (i0 + 3 < n2) {
        *(int4*)(loc + i0) = make_int4(p0, p1, p2, p3);
    } else {
        if (i0 + 0 < n2) loc[i0 + 0] = p0;
        if (i0 + 1 < n2) loc[i0 + 1] = p1;
        if (i0 + 2 < n2) loc[i0 + 2] = p2;
        if (i0 + 3 < n2) loc[i0 + 3] = p3;
    }
}

__global__ __launch_bounds__(256) void k_scan_mid(int* __restrict__ bsum, int nb)
{
    __shared__ int sh[256];
    __shared__ int carry;
    const int tid = threadIdx.x;
    if (tid == 0) carry = 0;
    __syncthreads();
    for (int base = 0; base < nb; base += 256) {
        int i = base + tid;
        int v = (i < nb) ? bsum[i] : 0;
        sh[tid] = v;
        __syncthreads();
        for (int o = 1; o < 256; o <<= 1) {
            int x = (tid >= o) ? sh[tid - o] : 0;
            __syncthreads();
            sh[tid] += x;
            __syncthreads();
        }
        int excl = sh[tid] - v + carry;
        int total = sh[255];
        if (i < nb) bsum[i] = excl;
        __syncthreads();
        if (tid == 0) carry += total;
        __syncthreads();
    }
}

__global__ __launch_bounds__(256) void k_scan_apply(
    const int* __restrict__ loc, const int* __restrict__ bsum,
    int* __restrict__ off, int* __restrict__ cursor, int n2)
{
    const int add = bsum[blockIdx.x];
    const int i0 = blockIdx.x * SCB + threadIdx.x * 4;
    if (i0 + 3 < n2) {
        int4 v = *(const int4*)(loc + i0);
        v.x += add; v.y += add; v.z += add; v.w += add;
        *(int4*)(off + i0) = v;
        *(int4*)(cursor + i0) = v;
    } else {
#pragma unroll
        for (int j = 0; j < 4; j++)
            if (i0 + j < n2) {
                int v = loc[i0 + j] + add;
                off[i0 + j] = v;
                cursor[i0 + j] = v;
            }
    }
}

// rec = (t<<20) | otherNode, via (node,t) cursor -> type-grouped per node.
__global__ __launch_bounds__(256) void k_fill8(
    const int* __restrict__ esrc, const int* __restrict__ edst,
    const int* __restrict__ etype, int* __restrict__ cursor,
    unsigned* __restrict__ rec, int ne, int Nn)
{
    const int oct = blockIdx.x & 7;
    const int slice = blockIdx.x >> 3;
    const int lo = (int)(((long long)oct * Nn) >> 3);
    const int hi = (int)(((long long)(oct + 1) * Nn) >> 3);
    for (int e = slice * 256 + threadIdx.x; e < ne; e += NSLICE * 256) {
        int t = etype[e], s = esrc[e], d = edst[e];
        if (d >= lo && d < hi) {
            int p = atomicAdd(&cursor[d * R_REL + t], 1);
            rec[p] = ((unsigned)t << 20) | (unsigned)s;   // fwd msg into d
        }
        if (s >= lo && s < hi) {
            int p2 = atomicAdd(&cursor[(Nn + s) * R_REL + t], 1);
            rec[p2] = ((unsigned)t << 20) | (unsigned)d;  // bwd msg into s
        }
    }
}

// Fused aggregate+GEMM, fp16, TWO type-chunks (5/4), persistent blocks.
// 1792 blocks x 4 waves, LDS ~21.9KB -> 7 blk/CU = 28 waves (87.5% cap).
// Per tile, per dir: prefetch 9 type-bounds + degS; per chunk: zero own
// Mt rows; group g streams node w*4+g's records of the chunk's types
// (4-deep predicated, half8/lane); RMW = single half8 add (v_pk_add_f16);
// barrier; MFMA f16 acc += Mt_chunk @ W[dir,chunk] (swapped); barrier.
// Epilogue per tile: + deg_t*b_t both dirs (fp32), fp32 out store.
__global__ __launch_bounds__(256, 7) void fused_rgcn(
    const _Float16* __restrict__ Hbf, const _Float16* __restrict__ Wt,
    const float* __restrict__ B18,
    const int* __restrict__ off3, const int* __restrict__ cur3,
    const unsigned* __restrict__ rec,
    float* __restrict__ out, int Nn, int ntiles)
{
    __shared__ __align__(16) _Float16 Mt[TN][MT_P];
    __shared__ float degS[2][TN][R_REL];

    const int tid = threadIdx.x;
    const int lane = tid & 63;
    const int w = tid >> 6;             // wave id; col slice w*32..w*32+31
    const int lr = lane & 15;
    const int lg = lane >> 4;
    const int grp = lg;                 // node-in-wave (aggregation role)
    const int gl = lr;                  // channel sub-lane: ch gl*8..gl*8+7
    const half8v z8 = (half8v){0, 0, 0, 0, 0, 0, 0, 0};
    const half8v* wt8 = (const half8v*)Wt;

#define RMW(rk, vk, tbase)                                                    \
    {                                                                         \
        int _tl = (int)((rk) >> 20) - (tbase);                                \
        half8v* _mp = (half8v*)(&Mt[w * 4 + grp][_tl * E_DIM + gl * 8]);      \
        *_mp = *_mp + (vk);                                                   \
    }

    for (int tile = blockIdx.x; tile < ntiles; tile += gridDim.x) {
        const int n0 = tile * TN;

        f32x4 acc[2];
        acc[0] = (f32x4){0.f, 0.f, 0.f, 0.f};
        acc[1] = (f32x4){0.f, 0.f, 0.f, 0.f};

#pragma unroll 1
        for (int dir = 0; dir < 2; dir++) {
            // Prefetch bounds: lane = jj*16 + tt (jj = node, tt = type).
            const int jj = lg, tt = lr;
            const int gnode_j = n0 + w * 4 + jj;
            int blo = 0x7F000000, bhi = 0x7F000000;
            if (gnode_j < Nn && tt < R_REL) {
                size_t sb = ((size_t)(dir ? (Nn + gnode_j) : gnode_j)) * R_REL + tt;
                blo = off3[sb];
                bhi = cur3[sb];
                degS[dir][w * 4 + jj][tt] = (float)(bhi - blo);
            }

#pragma unroll 1
            for (int ch = 0; ch < 2; ch++) {
                const int tbase = ch ? 5 : 0;
                const int tlen  = ch ? 4 : 5;

                // Zero this wave's Mt rows (full 648-half pitch: 81 half8).
#pragma unroll
                for (int rr = 0; rr < 4; rr++) {
                    _Float16* rowp = &Mt[w * 4 + rr][0];
                    *(half8v*)(rowp + (size_t)lane * 8) = z8;
                    if (lane < 17)
                        *(half8v*)(rowp + (size_t)(lane + 64) * 8) = z8;
                }

                // Per-group record range for this chunk.
                const int st_g = __shfl(blo, grp * 16 + tbase);
                const int en_g = __shfl(bhi, grp * 16 + tbase + tlen - 1);

                int ii = st_g;
                while (__any(ii < en_g)) {
                    bool a0 = ii + 0 < en_g;
                    bool a1 = ii + 1 < en_g;
                    bool a2 = ii + 2 < en_g;
                    bool a3 = ii + 3 < en_g;
                    unsigned r0 = 0, r1 = 0, r2 = 0, r3 = 0;
                    if (a0) r0 = rec[ii + 0];
                    if (a1) r1 = rec[ii + 1];
                    if (a2) r2 = rec[ii + 2];
                    if (a3) r3 = rec[ii + 3];
                    half8v v0 = z8, v1 = z8, v2 = z8, v3 = z8;
                    if (a0) v0 = *(const half8v*)(Hbf + (size_t)(r0 & 0xFFFFF) * E_DIM + gl * 8);
                    if (a1) v1 = *(const half8v*)(Hbf + (size_t)(r1 & 0xFFFFF) * E_DIM + gl * 8);
                    if (a2) v2 = *(const half8v*)(Hbf + (size_t)(r2 & 0xFFFFF) * E_DIM + gl * 8);
                    if (a3) v3 = *(const half8v*)(Hbf + (size_t)(r3 & 0xFFFFF) * E_DIM + gl * 8);
                    if (a0) RMW(r0, v0, tbase);
                    if (a1) RMW(r1, v1, tbase);
                    if (a2) RMW(r2, v2, tbase);
                    if (a3) RMW(r3, v3, tbase);
                    ii += 4;
                }
                __syncthreads();

                // ---- GEMM: acc += Mt_chunk @ W[dir, chunk types] ----
#pragma unroll 1
                for (int q = 0; q < tlen; q++) {
                    const int rel = dir * R_REL + tbase + q;
#pragma unroll
                    for (int s = 0; s < 4; s++) {
                        half8v b0 = wt8[(size_t)((((rel * 4 + w) * 4 + s) * 2 + 0) * 64) + lane];
                        half8v b1 = wt8[(size_t)((((rel * 4 + w) * 4 + s) * 2 + 1) * 64) + lane];
                        half8v a = *(const half8v*)(&Mt[lr][q * E_DIM + s * 32 + lg * 8]);
                        acc[0] = __builtin_amdgcn_mfma_f32_16x16x32_f16(b0, a, acc[0], 0, 0, 0);
                        acc[1] = __builtin_amdgcn_mfma_f32_16x16x32_f16(b1, a, acc[1], 0, 0, 0);
                    }
                }
                __syncthreads();   // before next chunk overwrites Mt
            }
        }

        // ---- epilogue: bias (deg_t * b_t) + store (guarded) ----
        const int gnode = n0 + lr;
        if (gnode < Nn) {
#pragma unroll 1
            for (int dir = 0; dir < 2; dir++) {
#pragma unroll 1
                for (int t = 0; t < R_REL; t++) {
                    float dg = degS[dir][lr][t];
                    if (dg != 0.f) {
                        const float* brow = B18 + (size_t)(dir * R_REL + t) * E_DIM + w * 32 + lg * 4;
                        float4 b0 = *(const float4*)(brow);
                        float4 b1 = *(const float4*)(brow + 16);
                        acc[0][0] += dg * b0.x; acc[0][1] += dg * b0.y;
                        acc[0][2] += dg * b0.z; acc[0][3] += dg * b0.w;
                        acc[1][0] += dg * b1.x; acc[1][1] += dg * b1.y;
                        acc[1][2] += dg * b1.z; acc[1][3] += dg * b1.w;
                    }
                }
            }
            float* po = out + (size_t)gnode * E_DIM + w * 32 + lg * 4;
            *(float4*)po = make_float4(acc[0][0], acc[0][1], acc[0][2], acc[0][3]);
            *(float4*)(po + 16) = make_float4(acc[1][0], acc[1][1], acc[1][2], acc[1][3]);
        }
        __syncthreads();   // degS/Mt reuse by next tile
    }
#undef RMW
}

// ---------- zero-workspace fallback (round-1, validated) ----------

__global__ __launch_bounds__(128) void direct_edge(
    const int* __restrict__ esrc, const int* __restrict__ edst,
    const int* __restrict__ etype,
    const float* __restrict__ H, const float* __restrict__ W2,
    const float* __restrict__ B2, float* __restrict__ out, int ne)
{
    __shared__ float hs[E_DIM];
    __shared__ float hd[E_DIM];
    int e = blockIdx.x;
    if (e >= ne) return;
    int t = etype[e], s = esrc[e], d = edst[e];
    int c = threadIdx.x;
    hs[c] = H[(size_t)s * E_DIM + c];
    hd[c] = H[(size_t)d * E_DIM + c];
    __syncthreads();
    const float* Wf = W2 + (size_t)t * E_DIM * E_DIM;
    const float* Wb = W2 + (size_t)(t + R_REL) * E_DIM * E_DIM;
    float accf = B2[(size_t)t * E_DIM + c];
    float accb = B2[(size_t)(t + R_REL) * E_DIM + c];
#pragma unroll 8
    for (int k = 0; k < E_DIM; k++) {
        accf += hs[k] * Wf[(size_t)k * E_DIM + c];
        accb += hd[k] * Wb[(size_t)k * E_DIM + c];
    }
    atomicAdd(&out[(size_t)d * E_DIM + c], accf);
    atomicAdd(&out[(size_t)s * E_DIM + c], accb);
}

extern "C" void kernel_launch(void* const* d_in, const int* in_sizes, int n_in,
                              void* d_out, int out_size, void* d_ws, size_t ws_size,
                              hipStream_t stream) {
    const int* edge_index = (const int*)d_in[0];   // [2][NE]
    const int* edge_type  = (const int*)d_in[1];   // [NE]
    const float* emb      = (const float*)d_in[2]; // [N][128]
    const float* weights  = (const float*)d_in[3]; // [L][18][128][128]
    const float* biases   = (const float*)d_in[4]; // [L][18][128]
    float* out = (float*)d_out;

    const int NE = in_sizes[1];
    const int Nn = in_sizes[2] / E_DIM;
    const int L  = in_sizes[3] / (2 * R_REL * E_DIM * E_DIM);

    const float* W2 = weights + (size_t)(L - 1) * 2 * R_REL * E_DIM * E_DIM;
    const float* B2 = biases  + (size_t)(L - 1) * 2 * R_REL * E_DIM;

    const int* esrc = edge_index;
    const int* edst = edge_index + NE;

    const int n3 = 2 * Nn * R_REL;                 // (node,dir,type) segments
    const int nb3 = (n3 + SCB - 1) / SCB;

    auto al = [](size_t x) { return (x + 255) & ~(size_t)255; };
    const size_t hbfBytes = al((size_t)Nn * E_DIM * 2);
    const size_t wtBytes  = al((size_t)2 * R_REL * E_DIM * E_DIM * 2);
    const size_t offBytes = al((size_t)n3 * 4);
    const size_t curBytes = al((size_t)n3 * 4);
    const size_t recBytes = al((size_t)2 * NE * 4);
    const size_t bsBytes  = al((size_t)nb3 * 4);
    const size_t need = hbfBytes + wtBytes + offBytes + curBytes + recBytes + bsBytes;

    if (ws_size >= need && Nn < (1 << 20)) {
        char* p = (char*)d_ws;
        _Float16* Hbf = (_Float16*)p;                    p += hbfBytes;
        _Float16* Wt  = (_Float16*)p;                    p += wtBytes;
        int* off3           = (int*)p;                   p += offBytes;
        int* cur3           = (int*)p;                   p += curBytes;
        unsigned* rec       = (unsigned*)p;              p += recBytes;
        int* bsum           = (int*)p;

        const long total8 = (long)Nn * (E_DIM / 8);
        const int hblocks = (int)((total8 + 255) / 256);

        hipMemsetAsync(off3, 0, (size_t)n3 * 4, stream);
        prep_count<<<18 + hblocks + 8 * NSLICE, 256, 0, stream>>>(
            emb, W2, esrc, edst, edge_type, Hbf, Wt, off3,
            total8, hblocks, NE, Nn);
        k_scan_part<<<nb3, 256, 0, stream>>>(off3, cur3, bsum, n3);
        k_scan_mid<<<1, 256, 0, stream>>>(bsum, nb3);
        k_scan_apply<<<nb3, 256, 0, stream>>>(cur3, bsum, off3, cur3, n3);
        k_fill8<<<8 * NSLICE, 256, 0, stream>>>(esrc, edst, edge_type,
                                                cur3, rec, NE, Nn);

        const int ntiles = (Nn + TN - 1) / TN;
        const int pgrid = (ntiles < 1792) ? ntiles : 1792;   // 7 blk/CU x 256 CU
        fused_rgcn<<<pgrid, 256, 0, stream>>>(
            Hbf, Wt, B2, off3, cur3, rec, out, Nn, ntiles);
        return;
    }

    // Fallback: direct per-edge GEMV with atomics.
    hipMemsetAsync(d_out, 0, (size_t)Nn * E_DIM * sizeof(float), stream);
    direct_edge<<<NE, 128, 0, stream>>>(esrc, edst, edge_type, emb, W2, B2, out, NE);
}